// Round 1
// baseline (173.103 us; speedup 1.0000x reference)
//
#include <hip/hip_runtime.h>

#define LN_EPS 1e-5f
#define C_M 256
#define C_Z 128
#define NO_BINS 15

// ---------------- m LayerNorm: one 64-lane wave per row of 256 f32 ----------
__global__ __launch_bounds__(256) void m_ln_kernel(
    const float* __restrict__ m, const float* __restrict__ w,
    const float* __restrict__ b, float* __restrict__ out, int nrows)
{
    const int wid  = threadIdx.x >> 6;   // wave in block (0..3)
    const int lane = threadIdx.x & 63;
    const int row  = blockIdx.x * 4 + wid;
    if (row >= nrows) return;

    const float4 v = reinterpret_cast<const float4*>(m + (long long)row * C_M)[lane];
    float s  = v.x + v.y + v.z + v.w;
    float s2 = v.x * v.x + v.y * v.y + v.z * v.z + v.w * v.w;
#pragma unroll
    for (int msk = 1; msk < 64; msk <<= 1) {
        s  += __shfl_xor(s,  msk);
        s2 += __shfl_xor(s2, msk);
    }
    const float mu  = s * (1.0f / C_M);
    const float var = s2 * (1.0f / C_M) - mu * mu;
    const float inv = rsqrtf(var + LN_EPS);

    const float4 wv = reinterpret_cast<const float4*>(w)[lane];
    const float4 bv = reinterpret_cast<const float4*>(b)[lane];
    float4 o;
    o.x = (v.x - mu) * inv * wv.x + bv.x;
    o.y = (v.y - mu) * inv * wv.y + bv.y;
    o.z = (v.z - mu) * inv * wv.z + bv.z;
    o.w = (v.w - mu) * inv * wv.w + bv.w;
    reinterpret_cast<float4*>(out + (long long)row * C_M)[lane] = o;
}

// ------- fused z: LayerNorm(z) + distogram-one-hot @ lin_w^T + lin_b --------
// one 32-lane half-wave per (i,j) row of 128 f32; 8 rows per 256-thread block
__global__ __launch_bounds__(256) void z_fused_kernel(
    const float* __restrict__ z, const float* __restrict__ x,
    const float* __restrict__ lin_w, const float* __restrict__ lin_b,
    const float* __restrict__ w, const float* __restrict__ b,
    float* __restrict__ out, int N)
{
    const int half = threadIdx.x >> 5;   // 0..7
    const int lane = threadIdx.x & 31;
    const long long row = (long long)blockIdx.x * 8 + half;
    const long long total = (long long)N * N;
    if (row >= total) return;

    const int i = (int)(row / N);
    const int j = (int)(row - (long long)i * N);

    const float4 v = reinterpret_cast<const float4*>(z + row * C_Z)[lane];
    float s  = v.x + v.y + v.z + v.w;
    float s2 = v.x * v.x + v.y * v.y + v.z * v.z + v.w * v.w;
#pragma unroll
    for (int msk = 1; msk < 32; msk <<= 1) {   // stays within the 32-lane group
        s  += __shfl_xor(s,  msk);
        s2 += __shfl_xor(s2, msk);
    }
    const float mu  = s * (1.0f / C_Z);
    const float var = s2 * (1.0f / C_Z) - mu * mu;
    const float inv = rsqrtf(var + LN_EPS);

    // pairwise squared distance, matching numpy f32 op order (no FMA contraction)
    const float dx = x[3 * i + 0] - x[3 * j + 0];
    const float dy = x[3 * i + 1] - x[3 * j + 1];
    const float dz = x[3 * i + 2] - x[3 * j + 2];
    const float d = __fadd_rn(__fadd_rn(__fmul_rn(dx, dx), __fmul_rn(dy, dy)),
                              __fmul_rn(dz, dz));

    // strict-inequality one-hot bin: bins = 3.25 + 1.25*k (exact in f32)
    int  cnt = 0;
    bool eq  = false;
#pragma unroll
    for (int k = 0; k < NO_BINS; ++k) {
        const float bk = 3.25f + 1.25f * (float)k;
        const float sq = bk * bk;
        cnt += (d > sq) ? 1 : 0;
        eq  |= (d == sq);
    }
    const int  bin   = cnt - 1;
    const bool valid = (cnt > 0) && (!eq) && (d < 1e8f);

    const int c = lane * 4;
    float e0 = 0.f, e1 = 0.f, e2 = 0.f, e3 = 0.f;
    if (valid) {
        e0 = lin_w[(c + 0) * NO_BINS + bin];
        e1 = lin_w[(c + 1) * NO_BINS + bin];
        e2 = lin_w[(c + 2) * NO_BINS + bin];
        e3 = lin_w[(c + 3) * NO_BINS + bin];
    }
    const float4 wv  = reinterpret_cast<const float4*>(w)[lane];
    const float4 bv  = reinterpret_cast<const float4*>(b)[lane];
    const float4 lbv = reinterpret_cast<const float4*>(lin_b)[lane];

    float4 o;
    o.x = (v.x - mu) * inv * wv.x + bv.x + lbv.x + e0;
    o.y = (v.y - mu) * inv * wv.y + bv.y + lbv.y + e1;
    o.z = (v.z - mu) * inv * wv.z + bv.z + lbv.z + e2;
    o.w = (v.w - mu) * inv * wv.w + bv.w + lbv.w + e3;
    reinterpret_cast<float4*>(out + row * C_Z)[lane] = o;
}

extern "C" void kernel_launch(void* const* d_in, const int* in_sizes, int n_in,
                              void* d_out, int out_size, void* d_ws, size_t ws_size,
                              hipStream_t stream) {
    const float* m      = (const float*)d_in[0];
    const float* z      = (const float*)d_in[1];
    const float* x      = (const float*)d_in[2];
    // d_in[3] = seqs (unused)
    const float* lin_w  = (const float*)d_in[4];
    const float* lin_b  = (const float*)d_in[5];
    const float* ln_m_w = (const float*)d_in[6];
    const float* ln_m_b = (const float*)d_in[7];
    const float* ln_z_w = (const float*)d_in[8];
    const float* ln_z_b = (const float*)d_in[9];

    const int N = in_sizes[0] / C_M;          // 768
    float* out_m = (float*)d_out;
    float* out_z = out_m + (long long)N * C_M;

    const int m_blocks = (N + 3) / 4;
    m_ln_kernel<<<m_blocks, 256, 0, stream>>>(m, ln_m_w, ln_m_b, out_m, N);

    const long long rows = (long long)N * N;
    const int z_blocks = (int)((rows + 7) / 8);
    z_fused_kernel<<<z_blocks, 256, 0, stream>>>(z, x, lin_w, lin_b,
                                                 ln_z_w, ln_z_b, out_z, N);
}

// Round 2
// 116.769 us; speedup vs baseline: 1.4824x; 1.4824x over previous
//
#include <hip/hip_runtime.h>

#define LN_EPS 1e-5f
#define C_M 256
#define C_Z 128
#define NO_BINS 15

typedef float f4 __attribute__((ext_vector_type(4)));

__device__ __forceinline__ f4 f4zero() { f4 t = {0.f, 0.f, 0.f, 0.f}; return t; }

// ---------------- m LayerNorm: one 64-lane wave per row of 256 f32 ----------
__global__ __launch_bounds__(256) void m_ln_kernel(
    const float* __restrict__ m, const float* __restrict__ w,
    const float* __restrict__ b, float* __restrict__ out, int nrows)
{
    const int wid  = threadIdx.x >> 6;
    const int lane = threadIdx.x & 63;
    const int row  = blockIdx.x * 4 + wid;
    if (row >= nrows) return;

    const f4 v = reinterpret_cast<const f4*>(m + (long long)row * C_M)[lane];
    float s  = v.x + v.y + v.z + v.w;
    float s2 = v.x * v.x + v.y * v.y + v.z * v.z + v.w * v.w;
#pragma unroll
    for (int msk = 1; msk < 64; msk <<= 1) {
        s  += __shfl_xor(s,  msk);
        s2 += __shfl_xor(s2, msk);
    }
    const float mu  = s * (1.0f / C_M);
    const float var = s2 * (1.0f / C_M) - mu * mu;
    const float inv = rsqrtf(var + LN_EPS);

    const f4 wv = reinterpret_cast<const f4*>(w)[lane];
    const f4 bv = reinterpret_cast<const f4*>(b)[lane];
    f4 o = (v - mu) * inv * wv + bv;
    reinterpret_cast<f4*>(out + (long long)row * C_M)[lane] = o;
}

// -------- bins precompute: bin index (or -1) per (i,j) into d_ws ------------
__global__ __launch_bounds__(256) void bins_kernel(
    const float* __restrict__ x, signed char* __restrict__ bins, int N)
{
    __shared__ float sqb[16];
    if (threadIdx.x < 16) {
        const float bk = 3.25f + 1.25f * (float)threadIdx.x;
        sqb[threadIdx.x] = (threadIdx.x < NO_BINS) ? bk * bk : -1.0f;
    }
    __syncthreads();
    const int i = blockIdx.x;
    const int j = blockIdx.y * 256 + threadIdx.x;
    if (j >= N) return;

    // exact numpy f32 op order (no FMA contraction)
    const float dx = x[3 * i + 0] - x[3 * j + 0];
    const float dy = x[3 * i + 1] - x[3 * j + 1];
    const float dz = x[3 * i + 2] - x[3 * j + 2];
    const float d = __fadd_rn(__fadd_rn(__fmul_rn(dx, dx), __fmul_rn(dy, dy)),
                              __fmul_rn(dz, dz));
    int cnt = 0;
#pragma unroll
    for (int k = 0; k < NO_BINS; ++k) {
        const float bk = 3.25f + 1.25f * (float)k;
        cnt += (d > bk * bk) ? 1 : 0;
    }
    // boundary equality d == sq[cnt] zeroes the one-hot (strict inequalities)
    const bool valid = (cnt > 0) && (d < 1e8f) && (d != sqb[cnt]);
    bins[(long long)i * N + j] = valid ? (signed char)(cnt - 1) : (signed char)(-1);
}

__device__ __forceinline__ int inline_bin(const float* __restrict__ x,
                                          const float* sqb, long long r, int N)
{
    const int i = (int)(r / N);
    const int j = (int)(r - (long long)i * N);
    const float dx = x[3 * i + 0] - x[3 * j + 0];
    const float dy = x[3 * i + 1] - x[3 * j + 1];
    const float dz = x[3 * i + 2] - x[3 * j + 2];
    const float d = __fadd_rn(__fadd_rn(__fmul_rn(dx, dx), __fmul_rn(dy, dy)),
                              __fmul_rn(dz, dz));
    int cnt = 0;
#pragma unroll
    for (int k = 0; k < NO_BINS; ++k) {
        const float bk = 3.25f + 1.25f * (float)k;
        cnt += (d > bk * bk) ? 1 : 0;
    }
    const bool valid = (cnt > 0) && (d < 1e8f) && (d != sqb[cnt]);
    return valid ? cnt - 1 : -1;
}

// ------- fused z: LayerNorm(z) + distogram embedding, grid-stride x2 --------
template <bool PRECOMP>
__global__ __launch_bounds__(256) void z_fused(
    const float* __restrict__ z, const float* __restrict__ x,
    const float* __restrict__ lin_w, const float* __restrict__ lin_b,
    const float* __restrict__ w, const float* __restrict__ b,
    const signed char* __restrict__ bins, float* __restrict__ out, int N)
{
    __shared__ float lw[NO_BINS * C_Z];   // transposed: [bin][c]
    __shared__ float sqb[16];
    const int tid = threadIdx.x;
    for (int t = tid; t < NO_BINS * C_Z; t += 256) {
        const int c = t / NO_BINS;
        const int bin = t - c * NO_BINS;
        lw[bin * C_Z + c] = lin_w[t];
    }
    if (tid < 16) {
        const float bk = 3.25f + 1.25f * (float)tid;
        sqb[tid] = (tid < NO_BINS) ? bk * bk : -1.0f;
    }
    __syncthreads();

    const int half = tid >> 5;
    const int lane = tid & 31;

    const f4 wv = reinterpret_cast<const f4*>(w)[lane];
    f4 bv = reinterpret_cast<const f4*>(b)[lane];
    bv += reinterpret_cast<const f4*>(lin_b)[lane];   // fold lin_b

    const long long total  = (long long)N * N;
    const long long stride = (long long)gridDim.x * 8;

    for (long long r = (long long)blockIdx.x * 8 + half; r < total; r += 2 * stride) {
        const long long ra = r;
        const long long rb = r + stride;
        const bool hb = rb < total;

        const f4 va = reinterpret_cast<const f4*>(z + ra * C_Z)[lane];
        f4 vb = f4zero();
        if (hb) vb = reinterpret_cast<const f4*>(z + rb * C_Z)[lane];

        int bina, binb;
        if constexpr (PRECOMP) {
            bina = (int)bins[ra];
            binb = hb ? (int)bins[rb] : -1;
        } else {
            bina = inline_bin(x, sqb, ra, N);
            binb = hb ? inline_bin(x, sqb, rb, N) : -1;
        }

        f4 ea = f4zero(), eb = f4zero();
        if (bina >= 0) ea = reinterpret_cast<const f4*>(lw + bina * C_Z)[lane];
        if (binb >= 0) eb = reinterpret_cast<const f4*>(lw + binb * C_Z)[lane];

        float sa  = va.x + va.y + va.z + va.w;
        float s2a = va.x * va.x + va.y * va.y + va.z * va.z + va.w * va.w;
        float sb  = vb.x + vb.y + vb.z + vb.w;
        float s2b = vb.x * vb.x + vb.y * vb.y + vb.z * vb.z + vb.w * vb.w;
#pragma unroll
        for (int msk = 1; msk < 32; msk <<= 1) {
            sa  += __shfl_xor(sa,  msk);
            s2a += __shfl_xor(s2a, msk);
            sb  += __shfl_xor(sb,  msk);
            s2b += __shfl_xor(s2b, msk);
        }
        const float mua  = sa * (1.0f / C_Z);
        const float inva = rsqrtf(s2a * (1.0f / C_Z) - mua * mua + LN_EPS);
        const float mub  = sb * (1.0f / C_Z);
        const float invb = rsqrtf(s2b * (1.0f / C_Z) - mub * mub + LN_EPS);

        f4 oa = (va - mua) * inva * wv + bv + ea;
        __builtin_nontemporal_store(oa, reinterpret_cast<f4*>(out + ra * C_Z) + lane);
        if (hb) {
            f4 ob = (vb - mub) * invb * wv + bv + eb;
            __builtin_nontemporal_store(ob, reinterpret_cast<f4*>(out + rb * C_Z) + lane);
        }
    }
}

extern "C" void kernel_launch(void* const* d_in, const int* in_sizes, int n_in,
                              void* d_out, int out_size, void* d_ws, size_t ws_size,
                              hipStream_t stream) {
    const float* m      = (const float*)d_in[0];
    const float* z      = (const float*)d_in[1];
    const float* x      = (const float*)d_in[2];
    // d_in[3] = seqs (unused)
    const float* lin_w  = (const float*)d_in[4];
    const float* lin_b  = (const float*)d_in[5];
    const float* ln_m_w = (const float*)d_in[6];
    const float* ln_m_b = (const float*)d_in[7];
    const float* ln_z_w = (const float*)d_in[8];
    const float* ln_z_b = (const float*)d_in[9];

    const int N = in_sizes[0] / C_M;          // 768
    float* out_m = (float*)d_out;
    float* out_z = out_m + (long long)N * C_M;

    m_ln_kernel<<<(N + 3) / 4, 256, 0, stream>>>(m, ln_m_w, ln_m_b, out_m, N);

    const long long rows = (long long)N * N;
    long long g = (rows + 15) / 16;           // each half-wave handles >=2 rows
    if (g > 4608) g = 4608;
    const int z_blocks = (int)g;

    const bool pre = ws_size >= (size_t)rows;
    signed char* bins = (signed char*)d_ws;
    if (pre) {
        dim3 bg((unsigned)N, (unsigned)((N + 255) / 256));
        bins_kernel<<<bg, 256, 0, stream>>>(x, bins, N);
        z_fused<true><<<z_blocks, 256, 0, stream>>>(z, x, lin_w, lin_b,
                                                    ln_z_w, ln_z_b, bins, out_z, N);
    } else {
        z_fused<false><<<z_blocks, 256, 0, stream>>>(z, x, lin_w, lin_b,
                                                     ln_z_w, ln_z_b, nullptr, out_z, N);
    }
}

// Round 3
// 116.058 us; speedup vs baseline: 1.4915x; 1.0061x over previous
//
#include <hip/hip_runtime.h>

#define LN_EPS 1e-5f
#define C_M 256
#define C_Z 128
#define NO_BINS 15

typedef float f4 __attribute__((ext_vector_type(4)));

__device__ __forceinline__ f4 f4zero() { f4 t = {0.f, 0.f, 0.f, 0.f}; return t; }

// one-hot bin index (or -1), strict inequalities, numpy f32 op order (no FMA)
__device__ __forceinline__ int bin_of(const float* __restrict__ x,
                                      const float* sqb, int i, int j)
{
    const float dx = x[3 * i + 0] - x[3 * j + 0];
    const float dy = x[3 * i + 1] - x[3 * j + 1];
    const float dz = x[3 * i + 2] - x[3 * j + 2];
    const float d = __fadd_rn(__fadd_rn(__fmul_rn(dx, dx), __fmul_rn(dy, dy)),
                              __fmul_rn(dz, dz));
    int cnt = 0;
#pragma unroll
    for (int k = 0; k < NO_BINS; ++k) {
        const float bk = 3.25f + 1.25f * (float)k;
        cnt += (d > bk * bk) ? 1 : 0;
    }
    // boundary equality d == sq[cnt] zeroes the one-hot (sqb[15] = -1 sentinel)
    return ((cnt > 0) && (d < 1e8f) && (d != sqb[cnt])) ? cnt - 1 : -1;
}

// single fused kernel: m LayerNorm (first blocks) + z LayerNorm+distogram
__global__ __launch_bounds__(256) void fused_kernel(
    const float* __restrict__ m, const float* __restrict__ ln_m_w,
    const float* __restrict__ ln_m_b, float* __restrict__ out_m, int m_rows,
    const float* __restrict__ z, const float* __restrict__ x,
    const float* __restrict__ lin_w, const float* __restrict__ lin_b,
    const float* __restrict__ ln_z_w, const float* __restrict__ ln_z_b,
    float* __restrict__ out_z, int N, int di, int rem)
{
    __shared__ float lw[NO_BINS * C_Z];   // transposed: [bin][c]
    __shared__ float sqb[16];
    const int tid = threadIdx.x;
    for (int t = tid; t < NO_BINS * C_Z; t += 256) {
        const int c = t / NO_BINS;
        const int bin = t - c * NO_BINS;
        lw[bin * C_Z + c] = lin_w[t];
    }
    if (tid < 16) {
        const float bk = 3.25f + 1.25f * (float)tid;
        sqb[tid] = (tid < NO_BINS) ? bk * bk : -1.0f;
    }
    __syncthreads();

    // ---- m LayerNorm: first ceil(m_rows/4) blocks, one wave per row ----
    if ((int)blockIdx.x < ((m_rows + 3) >> 2)) {
        const int wid    = tid >> 6;
        const int lane64 = tid & 63;
        const int row    = blockIdx.x * 4 + wid;
        if (row < m_rows) {
            const f4 v = reinterpret_cast<const f4*>(m + (long long)row * C_M)[lane64];
            float s  = v.x + v.y + v.z + v.w;
            float s2 = v.x * v.x + v.y * v.y + v.z * v.z + v.w * v.w;
#pragma unroll
            for (int msk = 1; msk < 64; msk <<= 1) {
                s  += __shfl_xor(s,  msk);
                s2 += __shfl_xor(s2, msk);
            }
            const float mu  = s * (1.0f / C_M);
            const float inv = rsqrtf(s2 * (1.0f / C_M) - mu * mu + LN_EPS);
            const f4 wv = reinterpret_cast<const f4*>(ln_m_w)[lane64];
            const f4 bv = reinterpret_cast<const f4*>(ln_m_b)[lane64];
            f4 o = (v - mu) * inv * wv + bv;
            reinterpret_cast<f4*>(out_m + (long long)row * C_M)[lane64] = o;
        }
    }

    // ---- z: one 32-lane half-wave per row, grid-stride, 2-row unroll ----
    const int half = tid >> 5;
    const int lane = tid & 31;

    const f4 wv = reinterpret_cast<const f4*>(ln_z_w)[lane];
    f4 bv = reinterpret_cast<const f4*>(ln_z_b)[lane];
    bv += reinterpret_cast<const f4*>(lin_b)[lane];   // fold lin_b

    const long long total  = (long long)N * N;
    const long long stride = (long long)gridDim.x * 8;

    long long r = (long long)blockIdx.x * 8 + half;
    int i = (int)(r / N);                  // once, outside the loop
    int j = (int)(r - (long long)i * N);

    for (; r < total; r += 2 * stride) {
        const long long ra = r;
        const long long rb = r + stride;
        const bool hb = rb < total;

        // incremental (i,j): one stride step = (+di, +rem) with wrap
        const int ia = i, ja = j;
        int ib = i + di, jb = j + rem;
        if (jb >= N) { jb -= N; ib += 1; }
        // advance two steps for next iteration
        i = ib + di; j = jb + rem;
        if (j >= N) { j -= N; i += 1; }

        const f4 va = reinterpret_cast<const f4*>(z + ra * C_Z)[lane];
        f4 vb = f4zero();
        if (hb) vb = reinterpret_cast<const f4*>(z + rb * C_Z)[lane];

        const int bina = bin_of(x, sqb, ia, ja);
        const int binb = hb ? bin_of(x, sqb, ib, jb) : -1;

        f4 ea = f4zero(), eb = f4zero();
        if (bina >= 0) ea = reinterpret_cast<const f4*>(lw + bina * C_Z)[lane];
        if (binb >= 0) eb = reinterpret_cast<const f4*>(lw + binb * C_Z)[lane];

        float sa  = va.x + va.y + va.z + va.w;
        float s2a = va.x * va.x + va.y * va.y + va.z * va.z + va.w * va.w;
        float sb  = vb.x + vb.y + vb.z + vb.w;
        float s2b = vb.x * vb.x + vb.y * vb.y + vb.z * vb.z + vb.w * vb.w;
#pragma unroll
        for (int msk = 1; msk < 32; msk <<= 1) {   // stays in the 32-lane group
            sa  += __shfl_xor(sa,  msk);
            s2a += __shfl_xor(s2a, msk);
            sb  += __shfl_xor(sb,  msk);
            s2b += __shfl_xor(s2b, msk);
        }
        const float mua  = sa * (1.0f / C_Z);
        const float inva = rsqrtf(s2a * (1.0f / C_Z) - mua * mua + LN_EPS);
        const float mub  = sb * (1.0f / C_Z);
        const float invb = rsqrtf(s2b * (1.0f / C_Z) - mub * mub + LN_EPS);

        f4 oa = (va - mua) * inva * wv + bv + ea;
        __builtin_nontemporal_store(oa, reinterpret_cast<f4*>(out_z + ra * C_Z) + lane);
        if (hb) {
            f4 ob = (vb - mub) * invb * wv + bv + eb;
            __builtin_nontemporal_store(ob, reinterpret_cast<f4*>(out_z + rb * C_Z) + lane);
        }
    }
}

extern "C" void kernel_launch(void* const* d_in, const int* in_sizes, int n_in,
                              void* d_out, int out_size, void* d_ws, size_t ws_size,
                              hipStream_t stream) {
    const float* m      = (const float*)d_in[0];
    const float* z      = (const float*)d_in[1];
    const float* x      = (const float*)d_in[2];
    // d_in[3] = seqs (unused)
    const float* lin_w  = (const float*)d_in[4];
    const float* lin_b  = (const float*)d_in[5];
    const float* ln_m_w = (const float*)d_in[6];
    const float* ln_m_b = (const float*)d_in[7];
    const float* ln_z_w = (const float*)d_in[8];
    const float* ln_z_b = (const float*)d_in[9];

    const int N = in_sizes[0] / C_M;          // 768
    float* out_m = (float*)d_out;
    float* out_z = out_m + (long long)N * C_M;

    // grid: multiple of unit so stride = grid*8 is a multiple of N (j invariant)
    const int gcd8 = (N % 8 == 0) ? 8 : (N % 4 == 0) ? 4 : (N % 2 == 0) ? 2 : 1;
    const int unit = N / gcd8;
    int g = (4608 / unit) * unit;
    if (g <= 0) g = unit;
    const int mB = (N + 3) / 4;               // blocks needed for the m rows
    if (g < mB) g = ((mB + unit - 1) / unit) * unit;

    const long long stride = (long long)g * 8;
    const int di  = (int)(stride / N);
    const int rem = (int)(stride % N);

    fused_kernel<<<g, 256, 0, stream>>>(m, ln_m_w, ln_m_b, out_m, N,
                                        z, x, lin_w, lin_b, ln_z_w, ln_z_b,
                                        out_z, N, di, rem);
}

// Round 4
// 109.950 us; speedup vs baseline: 1.5744x; 1.0556x over previous
//
#include <hip/hip_runtime.h>

#define LN_EPS 1e-5f
#define C_M 256
#define C_Z 128
#define NO_BINS 15

typedef float f4 __attribute__((ext_vector_type(4)));

__device__ __forceinline__ f4 f4zero() { f4 t = {0.f, 0.f, 0.f, 0.f}; return t; }

// one-hot bin index (or -1); strict inequalities; numpy f32 op order (no FMA)
__device__ __forceinline__ int bin_of_xj(const float* __restrict__ x,
                                         const float* sqb, int i,
                                         float xj0, float xj1, float xj2)
{
    const float dx = x[3 * i + 0] - xj0;
    const float dy = x[3 * i + 1] - xj1;
    const float dz = x[3 * i + 2] - xj2;
    const float d = __fadd_rn(__fadd_rn(__fmul_rn(dx, dx), __fmul_rn(dy, dy)),
                              __fmul_rn(dz, dz));
    int cnt = 0;
#pragma unroll
    for (int k = 0; k < NO_BINS; ++k) {
        const float bk = 3.25f + 1.25f * (float)k;
        cnt += (d > bk * bk) ? 1 : 0;
    }
    // boundary equality d == sq[cnt] zeroes the one-hot (sqb[15] = -1 sentinel)
    return ((cnt > 0) && (d < 1e8f) && (d != sqb[cnt])) ? cnt - 1 : -1;
}

__device__ __forceinline__ void ln_stats(const f4 v, float& s, float& s2)
{
    s  = v.x + v.y + v.z + v.w;
    s2 = v.x * v.x + v.y * v.y + v.z * v.z + v.w * v.w;
}

// ---- uniform fused kernel: requires N%16==0, grid = 2N blocks ----
// slot = bid*8+half in [0,16N); row_t = slot + t*16N, t in [0,N/16)
// => i = slot/N + 16t, j = slot%N constant per slot. No tail, no checks.
__global__ __launch_bounds__(256, 6) void fused_uniform(
    const float* __restrict__ m, const float* __restrict__ ln_m_w,
    const float* __restrict__ ln_m_b, float* __restrict__ out_m, int m_rows,
    const float* __restrict__ z, const float* __restrict__ x,
    const float* __restrict__ lin_w, const float* __restrict__ lin_b,
    const float* __restrict__ ln_z_w, const float* __restrict__ ln_z_b,
    float* __restrict__ out_z, int N, int iters)
{
    __shared__ float lw[NO_BINS * C_Z];   // transposed: [bin][c]
    __shared__ float sqb[16];
    const int tid = threadIdx.x;
    for (int t = tid; t < NO_BINS * C_Z; t += 256) {
        const int c = t / NO_BINS;
        const int bin = t - c * NO_BINS;
        lw[bin * C_Z + c] = lin_w[t];
    }
    if (tid < 16) {
        const float bk = 3.25f + 1.25f * (float)tid;
        sqb[tid] = (tid < NO_BINS) ? bk * bk : -1.0f;
    }
    __syncthreads();

    // ---- m LayerNorm: first ceil(m_rows/4) blocks, one wave per row ----
    if ((int)blockIdx.x < ((m_rows + 3) >> 2)) {
        const int wid    = tid >> 6;
        const int lane64 = tid & 63;
        const int row    = blockIdx.x * 4 + wid;
        if (row < m_rows) {
            const f4 v = reinterpret_cast<const f4*>(m + (long long)row * C_M)[lane64];
            float s, s2; ln_stats(v, s, s2);
#pragma unroll
            for (int msk = 1; msk < 64; msk <<= 1) {
                s  += __shfl_xor(s,  msk);
                s2 += __shfl_xor(s2, msk);
            }
            const float mu  = s * (1.0f / C_M);
            const float inv = rsqrtf(s2 * (1.0f / C_M) - mu * mu + LN_EPS);
            const f4 wv = reinterpret_cast<const f4*>(ln_m_w)[lane64];
            const f4 bv = reinterpret_cast<const f4*>(ln_m_b)[lane64];
            f4 o = (v - mu) * inv * wv + bv;
            reinterpret_cast<f4*>(out_m + (long long)row * C_M)[lane64] = o;
        }
    }

    // ---- z loop ----
    const int half = tid >> 5;
    const int lane = tid & 31;

    const f4 wv = reinterpret_cast<const f4*>(ln_z_w)[lane];
    f4 bv = reinterpret_cast<const f4*>(ln_z_b)[lane];
    bv += reinterpret_cast<const f4*>(lin_b)[lane];   // fold lin_b

    const int slot = (int)blockIdx.x * 8 + half;      // [0, 16N)
    const long long stride = (long long)N * 16;       // rows per step
    int i = slot / N;                                 // [0,16)
    const int j = slot - i * N;

    const float xj0 = x[3 * j + 0];
    const float xj1 = x[3 * j + 1];
    const float xj2 = x[3 * j + 2];

    long long r = slot;
    for (int t = 0; t < iters; t += 4) {
        const long long r0 = r, r1 = r + stride, r2 = r + 2 * stride, r3 = r + 3 * stride;
        const int i0 = i, i1 = i + 16, i2 = i + 32, i3 = i + 48;

        const f4 v0 = reinterpret_cast<const f4*>(z + r0 * C_Z)[lane];
        const f4 v1 = reinterpret_cast<const f4*>(z + r1 * C_Z)[lane];
        const f4 v2 = reinterpret_cast<const f4*>(z + r2 * C_Z)[lane];
        const f4 v3 = reinterpret_cast<const f4*>(z + r3 * C_Z)[lane];

        const int b0 = bin_of_xj(x, sqb, i0, xj0, xj1, xj2);
        const int b1 = bin_of_xj(x, sqb, i1, xj0, xj1, xj2);
        const int b2 = bin_of_xj(x, sqb, i2, xj0, xj1, xj2);
        const int b3 = bin_of_xj(x, sqb, i3, xj0, xj1, xj2);

        f4 e0 = f4zero(), e1 = f4zero(), e2 = f4zero(), e3 = f4zero();
        if (b0 >= 0) e0 = reinterpret_cast<const f4*>(lw + b0 * C_Z)[lane];
        if (b1 >= 0) e1 = reinterpret_cast<const f4*>(lw + b1 * C_Z)[lane];
        if (b2 >= 0) e2 = reinterpret_cast<const f4*>(lw + b2 * C_Z)[lane];
        if (b3 >= 0) e3 = reinterpret_cast<const f4*>(lw + b3 * C_Z)[lane];

        float s0, q0, s1, q1, s2, q2, s3, q3;
        ln_stats(v0, s0, q0); ln_stats(v1, s1, q1);
        ln_stats(v2, s2, q2); ln_stats(v3, s3, q3);
#pragma unroll
        for (int msk = 1; msk < 32; msk <<= 1) {   // within the 32-lane group
            s0 += __shfl_xor(s0, msk); q0 += __shfl_xor(q0, msk);
            s1 += __shfl_xor(s1, msk); q1 += __shfl_xor(q1, msk);
            s2 += __shfl_xor(s2, msk); q2 += __shfl_xor(q2, msk);
            s3 += __shfl_xor(s3, msk); q3 += __shfl_xor(q3, msk);
        }
        const float mu0 = s0 * (1.0f / C_Z), iv0 = rsqrtf(q0 * (1.0f / C_Z) - mu0 * mu0 + LN_EPS);
        const float mu1 = s1 * (1.0f / C_Z), iv1 = rsqrtf(q1 * (1.0f / C_Z) - mu1 * mu1 + LN_EPS);
        const float mu2 = s2 * (1.0f / C_Z), iv2 = rsqrtf(q2 * (1.0f / C_Z) - mu2 * mu2 + LN_EPS);
        const float mu3 = s3 * (1.0f / C_Z), iv3 = rsqrtf(q3 * (1.0f / C_Z) - mu3 * mu3 + LN_EPS);

        f4 o0 = (v0 - mu0) * iv0 * wv + bv + e0;
        f4 o1 = (v1 - mu1) * iv1 * wv + bv + e1;
        f4 o2 = (v2 - mu2) * iv2 * wv + bv + e2;
        f4 o3 = (v3 - mu3) * iv3 * wv + bv + e3;
        __builtin_nontemporal_store(o0, reinterpret_cast<f4*>(out_z + r0 * C_Z) + lane);
        __builtin_nontemporal_store(o1, reinterpret_cast<f4*>(out_z + r1 * C_Z) + lane);
        __builtin_nontemporal_store(o2, reinterpret_cast<f4*>(out_z + r2 * C_Z) + lane);
        __builtin_nontemporal_store(o3, reinterpret_cast<f4*>(out_z + r3 * C_Z) + lane);

        r += 4 * stride;
        i += 64;
    }
}

// ---- generic fallback (R3 structure, any N) ----
__device__ __forceinline__ int bin_of(const float* __restrict__ x,
                                      const float* sqb, int i, int j)
{
    return bin_of_xj(x, sqb, i, x[3 * j], x[3 * j + 1], x[3 * j + 2]);
}

__global__ __launch_bounds__(256) void fused_generic(
    const float* __restrict__ m, const float* __restrict__ ln_m_w,
    const float* __restrict__ ln_m_b, float* __restrict__ out_m, int m_rows,
    const float* __restrict__ z, const float* __restrict__ x,
    const float* __restrict__ lin_w, const float* __restrict__ lin_b,
    const float* __restrict__ ln_z_w, const float* __restrict__ ln_z_b,
    float* __restrict__ out_z, int N)
{
    __shared__ float lw[NO_BINS * C_Z];
    __shared__ float sqb[16];
    const int tid = threadIdx.x;
    for (int t = tid; t < NO_BINS * C_Z; t += 256) {
        const int c = t / NO_BINS;
        const int bin = t - c * NO_BINS;
        lw[bin * C_Z + c] = lin_w[t];
    }
    if (tid < 16) {
        const float bk = 3.25f + 1.25f * (float)tid;
        sqb[tid] = (tid < NO_BINS) ? bk * bk : -1.0f;
    }
    __syncthreads();

    if ((int)blockIdx.x < ((m_rows + 3) >> 2)) {
        const int wid    = tid >> 6;
        const int lane64 = tid & 63;
        const int row    = blockIdx.x * 4 + wid;
        if (row < m_rows) {
            const f4 v = reinterpret_cast<const f4*>(m + (long long)row * C_M)[lane64];
            float s, s2; ln_stats(v, s, s2);
#pragma unroll
            for (int msk = 1; msk < 64; msk <<= 1) {
                s  += __shfl_xor(s,  msk);
                s2 += __shfl_xor(s2, msk);
            }
            const float mu  = s * (1.0f / C_M);
            const float inv = rsqrtf(s2 * (1.0f / C_M) - mu * mu + LN_EPS);
            const f4 wv = reinterpret_cast<const f4*>(ln_m_w)[lane64];
            const f4 bv = reinterpret_cast<const f4*>(ln_m_b)[lane64];
            f4 o = (v - mu) * inv * wv + bv;
            reinterpret_cast<f4*>(out_m + (long long)row * C_M)[lane64] = o;
        }
    }

    const int half = tid >> 5;
    const int lane = tid & 31;
    const f4 wv = reinterpret_cast<const f4*>(ln_z_w)[lane];
    f4 bv = reinterpret_cast<const f4*>(ln_z_b)[lane];
    bv += reinterpret_cast<const f4*>(lin_b)[lane];

    const long long total  = (long long)N * N;
    const long long stride = (long long)gridDim.x * 8;
    for (long long r = (long long)blockIdx.x * 8 + half; r < total; r += stride) {
        const int i = (int)(r / N);
        const int j = (int)(r - (long long)i * N);
        const f4 v = reinterpret_cast<const f4*>(z + r * C_Z)[lane];
        const int bin = bin_of(x, sqb, i, j);
        f4 e = f4zero();
        if (bin >= 0) e = reinterpret_cast<const f4*>(lw + bin * C_Z)[lane];
        float s, s2; ln_stats(v, s, s2);
#pragma unroll
        for (int msk = 1; msk < 32; msk <<= 1) {
            s  += __shfl_xor(s,  msk);
            s2 += __shfl_xor(s2, msk);
        }
        const float mu  = s * (1.0f / C_Z);
        const float inv = rsqrtf(s2 * (1.0f / C_Z) - mu * mu + LN_EPS);
        f4 o = (v - mu) * inv * wv + bv + e;
        __builtin_nontemporal_store(o, reinterpret_cast<f4*>(out_z + r * C_Z) + lane);
    }
}

extern "C" void kernel_launch(void* const* d_in, const int* in_sizes, int n_in,
                              void* d_out, int out_size, void* d_ws, size_t ws_size,
                              hipStream_t stream) {
    const float* m      = (const float*)d_in[0];
    const float* z      = (const float*)d_in[1];
    const float* x      = (const float*)d_in[2];
    // d_in[3] = seqs (unused)
    const float* lin_w  = (const float*)d_in[4];
    const float* lin_b  = (const float*)d_in[5];
    const float* ln_m_w = (const float*)d_in[6];
    const float* ln_m_b = (const float*)d_in[7];
    const float* ln_z_w = (const float*)d_in[8];
    const float* ln_z_b = (const float*)d_in[9];

    const int N = in_sizes[0] / C_M;          // 768
    float* out_m = (float*)d_out;
    float* out_z = out_m + (long long)N * C_M;

    if ((N % 16) == 0 && 2 * N >= (N + 3) / 4) {
        // grid = 2N blocks (6/CU at N=768, all co-resident), N/16 iterations
        fused_uniform<<<2 * N, 256, 0, stream>>>(m, ln_m_w, ln_m_b, out_m, N,
                                                 z, x, lin_w, lin_b, ln_z_w, ln_z_b,
                                                 out_z, N, N / 16);
    } else {
        int g = 2048;
        const int mB = (N + 3) / 4;
        if (g < mB) g = mB;
        fused_generic<<<g, 256, 0, stream>>>(m, ln_m_w, ln_m_b, out_m, N,
                                             z, x, lin_w, lin_b, ln_z_w, ln_z_b,
                                             out_z, N);
    }
}